// Round 1
// baseline (4298.953 us; speedup 1.0000x reference)
//
#include <hip/hip_runtime.h>
#include <cstdint>
#include <cstddef>

// ---------------- constants ----------------
#define NN 10000
#define EE 160000
#define F_IN 128
#define HH 64
#define HEADS 8
#define LL 6
#define MM 512
#define OUT_DIM 64
#define EPSF 1e-5f

// ---------------- threefry (JAX-compatible) ----------------
struct U2 { uint32_t a, b; };

__host__ __device__ constexpr uint32_t rotl32(uint32_t x, uint32_t d) {
  return (x << d) | (x >> (32u - d));
}

__host__ __device__ constexpr U2 threefry2x32(uint32_t k1, uint32_t k2, uint32_t x0, uint32_t x1) {
  uint32_t ks2 = k1 ^ k2 ^ 0x1BD11BDAu;
  x0 += k1; x1 += k2;
  // group 1 (rot set 0), inject ks[1], ks[2]+1
  x0 += x1; x1 = rotl32(x1, 13); x1 ^= x0;
  x0 += x1; x1 = rotl32(x1, 15); x1 ^= x0;
  x0 += x1; x1 = rotl32(x1, 26); x1 ^= x0;
  x0 += x1; x1 = rotl32(x1, 6);  x1 ^= x0;
  x0 += k2; x1 += ks2 + 1u;
  // group 2 (rot set 1), inject ks[2], ks[0]+2
  x0 += x1; x1 = rotl32(x1, 17); x1 ^= x0;
  x0 += x1; x1 = rotl32(x1, 29); x1 ^= x0;
  x0 += x1; x1 = rotl32(x1, 16); x1 ^= x0;
  x0 += x1; x1 = rotl32(x1, 24); x1 ^= x0;
  x0 += ks2; x1 += k1 + 2u;
  // group 3 (rot set 0), inject ks[0], ks[1]+3
  x0 += x1; x1 = rotl32(x1, 13); x1 ^= x0;
  x0 += x1; x1 = rotl32(x1, 15); x1 ^= x0;
  x0 += x1; x1 = rotl32(x1, 26); x1 ^= x0;
  x0 += x1; x1 = rotl32(x1, 6);  x1 ^= x0;
  x0 += k1; x1 += k2 + 3u;
  // group 4 (rot set 1), inject ks[1], ks[2]+4
  x0 += x1; x1 = rotl32(x1, 17); x1 ^= x0;
  x0 += x1; x1 = rotl32(x1, 29); x1 ^= x0;
  x0 += x1; x1 = rotl32(x1, 16); x1 ^= x0;
  x0 += x1; x1 = rotl32(x1, 24); x1 ^= x0;
  x0 += k2; x1 += ks2 + 4u;
  // group 5 (rot set 0), inject ks[2], ks[0]+5
  x0 += x1; x1 = rotl32(x1, 13); x1 ^= x0;
  x0 += x1; x1 = rotl32(x1, 15); x1 ^= x0;
  x0 += x1; x1 = rotl32(x1, 26); x1 ^= x0;
  x0 += x1; x1 = rotl32(x1, 6);  x1 ^= x0;
  x0 += ks2; x1 += k1 + 5u;
  return U2{x0, x1};
}

// fold_in(key(42), data):  key(42) = (0,42); new key = block(key, (0, data))
__host__ __device__ constexpr U2 foldKey(uint32_t data) {
  return threefry2x32(0u, 42u, 0u, data);
}

// XLA ErfInv f32 (Giles)
__device__ inline float erfinv_f32(float x) {
  float w = -log1pf(-x * x);
  float p;
  if (w < 5.0f) {
    w -= 2.5f;
    p = 2.81022636e-08f;
    p = fmaf(p, w, 3.43273939e-07f);
    p = fmaf(p, w, -3.5233877e-06f);
    p = fmaf(p, w, -4.39150654e-06f);
    p = fmaf(p, w, 0.00021858087f);
    p = fmaf(p, w, -0.00125372503f);
    p = fmaf(p, w, -0.00417768164f);
    p = fmaf(p, w, 0.246640727f);
    p = fmaf(p, w, 1.50140941f);
  } else {
    w = sqrtf(w) - 3.0f;
    p = -0.000200214257f;
    p = fmaf(p, w, 0.000100950558f);
    p = fmaf(p, w, 0.00134934322f);
    p = fmaf(p, w, -0.00367342844f);
    p = fmaf(p, w, 0.00573950773f);
    p = fmaf(p, w, -0.0076224613f);
    p = fmaf(p, w, 0.00943887047f);
    p = fmaf(p, w, 1.00167406f);
    p = fmaf(p, w, 2.83297682f);
  }
  return p * x;
}

// jax.random.normal element: partitionable threefry counter layout
// counter64 = idx -> (hi=0, lo=idx); bits = out1 ^ out2 (32-bit draw)
__device__ inline float jax_normal(uint32_t k1, uint32_t k2, uint32_t idx) {
  U2 r = threefry2x32(k1, k2, 0u, idx);
  uint32_t bits = r.a ^ r.b;
  uint32_t fb = (bits >> 9) | 0x3f800000u;
  float f = __uint_as_float(fb) - 1.0f;          // [0,1)
  const float lo = -0.99999994f;                 // nextafter(-1,0)
  float u = f * 2.0f + lo;                       // (hi-lo) == 2.0f exactly in f32
  u = fmaxf(lo, u);
  return 1.41421356f * erfinv_f32(u);
}

// ---------------- helpers ----------------
__device__ inline float waveSum(float v) {
  v += __shfl_xor(v, 32, 64);
  v += __shfl_xor(v, 16, 64);
  v += __shfl_xor(v, 8, 64);
  v += __shfl_xor(v, 4, 64);
  v += __shfl_xor(v, 2, 64);
  v += __shfl_xor(v, 1, 64);
  return v;
}

// monotonic float<->uint encode for atomic max (init 0 == "below -inf")
__device__ inline unsigned int fenc(float f) {
  unsigned int u = __float_as_uint(f);
  return (u & 0x80000000u) ? ~u : (u | 0x80000000u);
}
__device__ inline float fdec(unsigned int u) {
  return __uint_as_float((u & 0x80000000u) ? (u & 0x7FFFFFFFu) : ~u);
}

// ---------------- kernels ----------------

// encoder: h = relu(LN(x @ W + b; g,be)) + cm*0.1   [N,64], one wave per row
__global__ __launch_bounds__(64) void encoder_kernel(
    const float* __restrict__ x, const float* __restrict__ W, const float* __restrict__ b,
    const float* __restrict__ g, const float* __restrict__ be, const float* __restrict__ cm,
    float* __restrict__ h) {
  __shared__ float xs[F_IN];
  int n = blockIdx.x, l = threadIdx.x;
  xs[l]      = x[(size_t)n * F_IN + l];
  xs[l + 64] = x[(size_t)n * F_IN + 64 + l];
  __syncthreads();
  float acc = b[l];
  #pragma unroll 8
  for (int k = 0; k < F_IN; k++) acc = fmaf(xs[k], W[k * HH + l], acc);
  float mu = waveSum(acc) * (1.0f / 64.0f);
  float d = acc - mu;
  float var = waveSum(d * d) * (1.0f / 64.0f);
  float y = fmaf(d / sqrtf(var + EPSF), g[l], be[l]);
  y = fmaxf(y, 0.0f);
  h[(size_t)n * HH + l] = fmaf(cm[l], 0.1f, y);
}

// C[N,M] = A[N,K] @ B[K,M] + bias ; 64x64 tile, BK=32, 256 thr, 4x4 per thread
__global__ __launch_bounds__(256) void gemm_bias_f32(
    const float* __restrict__ A, const float* __restrict__ B,
    const float* __restrict__ bias, float* __restrict__ C,
    int NR, int K, int M) {
  __shared__ float As[32][65];
  __shared__ float Bs[32][64];
  int t = threadIdx.x;
  int tx = t & 15, ty = t >> 4;
  int row0 = blockIdx.x * 64;
  int col0 = blockIdx.y * 64;
  float acc[4][4] = {};
  for (int k0 = 0; k0 < K; k0 += 32) {
    #pragma unroll
    for (int p = 0; p < 2; ++p) {  // A: 64 rows x 32 cols
      int li = p * 256 + t;
      int r = li >> 3, c4 = li & 7;
      int gr = row0 + r;
      float4 v = make_float4(0.f, 0.f, 0.f, 0.f);
      if (gr < NR) v = *(const float4*)(A + (size_t)gr * K + k0 + c4 * 4);
      As[c4 * 4 + 0][r] = v.x; As[c4 * 4 + 1][r] = v.y;
      As[c4 * 4 + 2][r] = v.z; As[c4 * 4 + 3][r] = v.w;
    }
    #pragma unroll
    for (int p = 0; p < 2; ++p) {  // B: 32 rows x 64 cols
      int li = p * 256 + t;
      int r = li >> 4, c4 = li & 15;
      *(float4*)(&Bs[r][c4 * 4]) = *(const float4*)(B + (size_t)(k0 + r) * M + col0 + c4 * 4);
    }
    __syncthreads();
    #pragma unroll
    for (int kk = 0; kk < 32; ++kk) {
      float a[4], bb[4];
      #pragma unroll
      for (int i = 0; i < 4; i++) a[i] = As[kk][ty + 16 * i];
      #pragma unroll
      for (int j = 0; j < 4; j++) bb[j] = Bs[kk][tx + 16 * j];
      #pragma unroll
      for (int i = 0; i < 4; i++)
        #pragma unroll
        for (int j = 0; j < 4; j++) acc[i][j] = fmaf(a[i], bb[j], acc[i][j]);
    }
    __syncthreads();
  }
  #pragma unroll
  for (int i = 0; i < 4; i++) {
    int r = row0 + ty + 16 * i;
    if (r >= NR) continue;
    #pragma unroll
    for (int j = 0; j < 4; j++) {
      int c = col0 + tx + 16 * j;
      C[(size_t)r * M + c] = acc[i][j] + bias[c];
    }
  }
}

// In-place over Y[N,512]: o = relu(LN(Y; g,be)); feats (=|+=) o; Y = o + noise*cf
__global__ __launch_bounds__(256) void ln_relu_acc(
    float* __restrict__ Y, const float* __restrict__ g, const float* __restrict__ be,
    float* __restrict__ feats, int firstDepth, int writeCur,
    uint32_t k1, uint32_t k2, float cf) {
  int n = blockIdx.x, t = threadIdx.x;
  size_t base = (size_t)n * MM;
  float v0 = Y[base + t], v1 = Y[base + t + 256];
  int wid = t >> 6, lane = t & 63;
  __shared__ float red[8];
  float s = waveSum(v0 + v1);
  if (lane == 0) red[wid] = s;
  __syncthreads();
  float mu = (red[0] + red[1] + red[2] + red[3]) * (1.0f / 512.0f);
  float d0 = v0 - mu, d1 = v1 - mu;
  float q = waveSum(d0 * d0 + d1 * d1);
  if (lane == 0) red[4 + wid] = q;
  __syncthreads();
  float var = (red[4] + red[5] + red[6] + red[7]) * (1.0f / 512.0f);
  float inv = 1.0f / sqrtf(var + EPSF);
  float o0 = fmaxf(fmaf(d0 * inv, g[t], be[t]), 0.0f);
  float o1 = fmaxf(fmaf(d1 * inv, g[t + 256], be[t + 256]), 0.0f);
  if (firstDepth) { feats[base + t] = o0; feats[base + t + 256] = o1; }
  else            { feats[base + t] += o0; feats[base + t + 256] += o1; }
  if (writeCur) {
    Y[base + t]       = fmaf(jax_normal(k1, k2, (uint32_t)(base + t)), cf, o0);
    Y[base + t + 256] = fmaf(jax_normal(k1, k2, (uint32_t)(base + t + 256)), cf, o1);
  }
}

// a_i/a_j per node & head: one wave per node
__global__ __launch_bounds__(64) void gat_scores(
    const float* __restrict__ feats, const float* __restrict__ attL,
    float* __restrict__ ai, float* __restrict__ aj) {
  int n = blockIdx.x, l = threadIdx.x;
  const float inv3 = 1.0f / 3.0f;
  #pragma unroll
  for (int hh = 0; hh < HEADS; ++hh) {
    float v = feats[(size_t)n * MM + hh * HH + l] * inv3;
    float si = waveSum(v * attL[hh * 128 + l]);
    float sj = waveSum(v * attL[hh * 128 + 64 + l]);
    if (l == 0) { ai[n * HEADS + hh] = si; aj[n * HEADS + hh] = sj; }
  }
}

__global__ __launch_bounds__(256) void gat_alpha(
    const int* __restrict__ src, const int* __restrict__ dst,
    const float* __restrict__ ai, const float* __restrict__ aj,
    float* __restrict__ alpha, unsigned int* __restrict__ amax) {
  int e = blockIdx.x * blockDim.x + threadIdx.x;
  if (e >= EE) return;
  int s = src[e], d = dst[e];
  #pragma unroll
  for (int hh = 0; hh < HEADS; ++hh) {
    float a = ai[d * HEADS + hh] + aj[s * HEADS + hh];
    a = (a >= 0.0f) ? a : 0.2f * a;  // leaky_relu 0.2
    alpha[(size_t)e * HEADS + hh] = a;
    atomicMax(&amax[d * HEADS + hh], fenc(a));
  }
}

__global__ __launch_bounds__(256) void gat_ex(
    const int* __restrict__ dst, float* __restrict__ alpha,
    const unsigned int* __restrict__ amax, float* __restrict__ denom) {
  int e = blockIdx.x * blockDim.x + threadIdx.x;
  if (e >= EE) return;
  int d = dst[e];
  #pragma unroll
  for (int hh = 0; hh < HEADS; ++hh) {
    float m = fdec(amax[d * HEADS + hh]);
    float ex = expf(alpha[(size_t)e * HEADS + hh] - m);
    alpha[(size_t)e * HEADS + hh] = ex;
    atomicAdd(&denom[d * HEADS + hh], ex);
  }
}

// block per edge, 64 lanes = channels; 8 heads looped; atomic scatter to agg[dst]
__global__ __launch_bounds__(64) void gat_agg(
    const int* __restrict__ src, const int* __restrict__ dst,
    const float* __restrict__ exw, const float* __restrict__ denom,
    const float* __restrict__ feats, float* __restrict__ agg) {
  int e = blockIdx.x, l = threadIdx.x;
  int s = src[e], d = dst[e];
  const float inv3 = 1.0f / 3.0f;
  #pragma unroll
  for (int hh = 0; hh < HEADS; ++hh) {
    float w = exw[(size_t)e * HEADS + hh] / denom[d * HEADS + hh];
    float val = feats[(size_t)s * MM + hh * HH + l] * (inv3 * w);
    atomicAdd(&agg[(size_t)d * MM + hh * HH + l], val);
  }
}

// head-mean -> gate MLP -> blend -> resid accum -> plain LN back into h
__global__ __launch_bounds__(128) void gate_blend(
    const float* __restrict__ agg, const float* __restrict__ W1, const float* __restrict__ b1,
    const float* __restrict__ W2, const float* __restrict__ b2,
    float* __restrict__ h, float* __restrict__ resid) {
  __shared__ float hn[64];
  __shared__ float z[128];
  int n = blockIdx.x, t = threadIdx.x;
  if (t < 64) {
    float s = 0.0f;
    #pragma unroll
    for (int hh = 0; hh < HEADS; ++hh) s += agg[(size_t)n * MM + hh * HH + t];
    hn[t] = s * 0.125f;
  }
  __syncthreads();
  float zz = b1[t];
  #pragma unroll 8
  for (int k = 0; k < 64; k++) zz = fmaf(hn[k], W1[k * 128 + t], zz);
  z[t] = fmaxf(zz, 0.0f);
  __syncthreads();
  if (t < 64) {
    float y = b2[t];
    #pragma unroll 8
    for (int k = 0; k < 128; k++) y = fmaf(z[k], W2[k * 64 + t], y);
    float gate = 1.0f / (1.0f + expf(-tanhf(y)));
    float hp = h[(size_t)n * HH + t];
    float hb = gate * hn[t] + (1.0f - gate) * hp;
    resid[(size_t)n * HH + t] += hb;
    float mu = waveSum(hb) * (1.0f / 64.0f);
    float dd = hb - mu;
    float var = waveSum(dd * dd) * (1.0f / 64.0f);
    h[(size_t)n * HH + t] = dd / sqrtf(var + EPSF);
  }
}

// decoders; out layout: state[N], imp[N], chaos[N], evo[N*64], h_multi[N*64]
__global__ __launch_bounds__(64) void decoder_kernel(
    const float* __restrict__ resid,
    const float* __restrict__ dsW, const float* __restrict__ dsb,
    const float* __restrict__ diW, const float* __restrict__ dib,
    const float* __restrict__ dcW, const float* __restrict__ dcb,
    const float* __restrict__ deW, const float* __restrict__ deb,
    float* __restrict__ out) {
  __shared__ float hm[64];
  int n = blockIdx.x, l = threadIdx.x;
  float v = resid[(size_t)n * HH + l] * (1.0f / 6.0f);
  hm[l] = v;
  float s1 = waveSum(v * dsW[l]);
  float s2 = waveSum(v * diW[l]);
  float s3 = waveSum(v * dcW[l]);
  if (l == 0) {
    out[n]          = s1 + dsb[0];
    out[NN + n]     = s2 + dib[0];
    out[2 * NN + n] = s3 + dcb[0];
  }
  __syncthreads();
  float e = deb[l];
  #pragma unroll 8
  for (int k = 0; k < 64; k++) e = fmaf(hm[k], deW[k * OUT_DIM + l], e);
  out[3 * NN + (size_t)n * OUT_DIM + l] = e;
  out[3 * NN + (size_t)NN * OUT_DIM + (size_t)n * HH + l] = v;
}

// ---------------- launch ----------------
extern "C" void kernel_launch(void* const* d_in, const int* in_sizes, int n_in,
                              void* d_out, int out_size, void* d_ws, size_t ws_size,
                              hipStream_t stream) {
  const float* x        = (const float*)d_in[0];
  const int*   ei       = (const int*)d_in[1];
  const float* enc_W    = (const float*)d_in[2];
  const float* enc_b    = (const float*)d_in[3];
  const float* enc_g    = (const float*)d_in[4];
  const float* enc_beta = (const float*)d_in[5];
  const float* cm       = (const float*)d_in[6];
  const float* tW0 = (const float*)d_in[7];  const float* tb0 = (const float*)d_in[8];
  const float* tg0 = (const float*)d_in[9];  const float* tbe0 = (const float*)d_in[10];
  const float* tW1 = (const float*)d_in[11]; const float* tb1 = (const float*)d_in[12];
  const float* tg1 = (const float*)d_in[13]; const float* tbe1 = (const float*)d_in[14];
  const float* tW2 = (const float*)d_in[15]; const float* tb2 = (const float*)d_in[16];
  const float* tg2 = (const float*)d_in[17]; const float* tbe2 = (const float*)d_in[18];
  const float* att = (const float*)d_in[19];
  const float* evo_W1 = (const float*)d_in[20]; const float* evo_b1 = (const float*)d_in[21];
  const float* evo_W2 = (const float*)d_in[22]; const float* evo_b2 = (const float*)d_in[23];
  const float* dsW = (const float*)d_in[24]; const float* dsb = (const float*)d_in[25];
  const float* diW = (const float*)d_in[26]; const float* dib = (const float*)d_in[27];
  const float* dcW = (const float*)d_in[28]; const float* dcb = (const float*)d_in[29];
  const float* deW = (const float*)d_in[30]; const float* deb = (const float*)d_in[31];
  float* out = (float*)d_out;

  const int* src = ei;
  const int* dst = ei + EE;

  float* ws = (float*)d_ws;
  size_t o = 0;
  float* bufA  = ws + o; o += (size_t)NN * MM;   // 5.12M
  float* bufB  = ws + o; o += (size_t)NN * MM;   // also reused as agg
  float* feats = ws + o; o += (size_t)NN * MM;
  float* h     = ws + o; o += (size_t)NN * HH;
  float* resid = ws + o; o += (size_t)NN * HH;
  float* ai    = ws + o; o += (size_t)NN * HEADS;
  float* aj    = ws + o; o += (size_t)NN * HEADS;
  unsigned int* amax = (unsigned int*)(ws + o); o += (size_t)NN * HEADS;  // amax+denom contiguous
  float* denom = ws + o; o += (size_t)NN * HEADS;
  float* alpha = ws + o; o += (size_t)EE * HEADS;
  (void)ws_size; (void)n_in; (void)in_sizes; (void)out_size;

  encoder_kernel<<<NN, 64, 0, stream>>>(x, enc_W, enc_b, enc_g, enc_beta, cm, h);
  hipMemsetAsync(resid, 0, (size_t)NN * HH * sizeof(float), stream);

  dim3 gg((NN + 63) / 64, MM / 64);
  for (int i = 0; i < LL; ++i) {
    float cf = (float)(0.1 * (1.0 + 0.1 * (double)i));
    U2 fk0 = foldKey((uint32_t)(i * 10 + 0));
    U2 fk1 = foldKey((uint32_t)(i * 10 + 1));

    gemm_bias_f32<<<gg, 256, 0, stream>>>(h,    tW0 + (size_t)i * HH * MM, tb0 + (size_t)i * MM, bufA, NN, HH, MM);
    ln_relu_acc<<<NN, 256, 0, stream>>>(bufA, tg0 + (size_t)i * MM, tbe0 + (size_t)i * MM, feats, 1, 1, fk0.a, fk0.b, cf);
    gemm_bias_f32<<<gg, 256, 0, stream>>>(bufA, tW1 + (size_t)i * MM * MM, tb1 + (size_t)i * MM, bufB, NN, MM, MM);
    ln_relu_acc<<<NN, 256, 0, stream>>>(bufB, tg1 + (size_t)i * MM, tbe1 + (size_t)i * MM, feats, 0, 1, fk1.a, fk1.b, cf);
    gemm_bias_f32<<<gg, 256, 0, stream>>>(bufB, tW2 + (size_t)i * MM * MM, tb2 + (size_t)i * MM, bufA, NN, MM, MM);
    ln_relu_acc<<<NN, 256, 0, stream>>>(bufA, tg2 + (size_t)i * MM, tbe2 + (size_t)i * MM, feats, 0, 0, 0u, 0u, 0.0f);

    hipMemsetAsync(amax, 0, (size_t)NN * HEADS * 2 * sizeof(unsigned int), stream); // amax + denom
    hipMemsetAsync(bufB, 0, (size_t)NN * MM * sizeof(float), stream);               // agg

    gat_scores<<<NN, 64, 0, stream>>>(feats, att + (size_t)i * HEADS * 2 * HH, ai, aj);
    gat_alpha<<<(EE + 255) / 256, 256, 0, stream>>>(src, dst, ai, aj, alpha, amax);
    gat_ex<<<(EE + 255) / 256, 256, 0, stream>>>(dst, alpha, amax, denom);
    gat_agg<<<EE, 64, 0, stream>>>(src, dst, alpha, denom, feats, bufB);
    gate_blend<<<NN, 128, 0, stream>>>(bufB, evo_W1, evo_b1, evo_W2, evo_b2, h, resid);
  }

  decoder_kernel<<<NN, 64, 0, stream>>>(resid, dsW, dsb, diW, dib, dcW, dcb, deW, deb, out);
}

// Round 2
// 2324.938 us; speedup vs baseline: 1.8491x; 1.8491x over previous
//
#include <hip/hip_runtime.h>
#include <cstdint>
#include <cstddef>

// ---------------- constants ----------------
#define NN 10000
#define EE 160000
#define F_IN 128
#define HH 64
#define HEADS 8
#define LL 6
#define MM 512
#define OUT_DIM 64
#define EPSF 1e-5f

// ---------------- threefry (JAX-compatible) ----------------
struct U2 { uint32_t a, b; };

__host__ __device__ constexpr uint32_t rotl32(uint32_t x, uint32_t d) {
  return (x << d) | (x >> (32u - d));
}

__host__ __device__ constexpr U2 threefry2x32(uint32_t k1, uint32_t k2, uint32_t x0, uint32_t x1) {
  uint32_t ks2 = k1 ^ k2 ^ 0x1BD11BDAu;
  x0 += k1; x1 += k2;
  x0 += x1; x1 = rotl32(x1, 13); x1 ^= x0;
  x0 += x1; x1 = rotl32(x1, 15); x1 ^= x0;
  x0 += x1; x1 = rotl32(x1, 26); x1 ^= x0;
  x0 += x1; x1 = rotl32(x1, 6);  x1 ^= x0;
  x0 += k2; x1 += ks2 + 1u;
  x0 += x1; x1 = rotl32(x1, 17); x1 ^= x0;
  x0 += x1; x1 = rotl32(x1, 29); x1 ^= x0;
  x0 += x1; x1 = rotl32(x1, 16); x1 ^= x0;
  x0 += x1; x1 = rotl32(x1, 24); x1 ^= x0;
  x0 += ks2; x1 += k1 + 2u;
  x0 += x1; x1 = rotl32(x1, 13); x1 ^= x0;
  x0 += x1; x1 = rotl32(x1, 15); x1 ^= x0;
  x0 += x1; x1 = rotl32(x1, 26); x1 ^= x0;
  x0 += x1; x1 = rotl32(x1, 6);  x1 ^= x0;
  x0 += k1; x1 += k2 + 3u;
  x0 += x1; x1 = rotl32(x1, 17); x1 ^= x0;
  x0 += x1; x1 = rotl32(x1, 29); x1 ^= x0;
  x0 += x1; x1 = rotl32(x1, 16); x1 ^= x0;
  x0 += x1; x1 = rotl32(x1, 24); x1 ^= x0;
  x0 += k2; x1 += ks2 + 4u;
  x0 += x1; x1 = rotl32(x1, 13); x1 ^= x0;
  x0 += x1; x1 = rotl32(x1, 15); x1 ^= x0;
  x0 += x1; x1 = rotl32(x1, 26); x1 ^= x0;
  x0 += x1; x1 = rotl32(x1, 6);  x1 ^= x0;
  x0 += ks2; x1 += k1 + 5u;
  return U2{x0, x1};
}

__host__ __device__ constexpr U2 foldKey(uint32_t data) {
  return threefry2x32(0u, 42u, 0u, data);
}

// XLA ErfInv f32 (Giles)
__device__ inline float erfinv_f32(float x) {
  float w = -log1pf(-x * x);
  float p;
  if (w < 5.0f) {
    w -= 2.5f;
    p = 2.81022636e-08f;
    p = fmaf(p, w, 3.43273939e-07f);
    p = fmaf(p, w, -3.5233877e-06f);
    p = fmaf(p, w, -4.39150654e-06f);
    p = fmaf(p, w, 0.00021858087f);
    p = fmaf(p, w, -0.00125372503f);
    p = fmaf(p, w, -0.00417768164f);
    p = fmaf(p, w, 0.246640727f);
    p = fmaf(p, w, 1.50140941f);
  } else {
    w = sqrtf(w) - 3.0f;
    p = -0.000200214257f;
    p = fmaf(p, w, 0.000100950558f);
    p = fmaf(p, w, 0.00134934322f);
    p = fmaf(p, w, -0.00367342844f);
    p = fmaf(p, w, 0.00573950773f);
    p = fmaf(p, w, -0.0076224613f);
    p = fmaf(p, w, 0.00943887047f);
    p = fmaf(p, w, 1.00167406f);
    p = fmaf(p, w, 2.83297682f);
  }
  return p * x;
}

__device__ inline float jax_normal(uint32_t k1, uint32_t k2, uint32_t idx) {
  U2 r = threefry2x32(k1, k2, 0u, idx);
  uint32_t bits = r.a ^ r.b;
  uint32_t fb = (bits >> 9) | 0x3f800000u;
  float f = __uint_as_float(fb) - 1.0f;
  const float lo = -0.99999994f;
  float u = f * 2.0f + lo;
  u = fmaxf(lo, u);
  return 1.41421356f * erfinv_f32(u);
}

// ---------------- helpers ----------------
__device__ inline float waveSum(float v) {
  v += __shfl_xor(v, 32, 64);
  v += __shfl_xor(v, 16, 64);
  v += __shfl_xor(v, 8, 64);
  v += __shfl_xor(v, 4, 64);
  v += __shfl_xor(v, 2, 64);
  v += __shfl_xor(v, 1, 64);
  return v;
}
__device__ inline float waveMax(float v) {
  v = fmaxf(v, __shfl_xor(v, 32, 64));
  v = fmaxf(v, __shfl_xor(v, 16, 64));
  v = fmaxf(v, __shfl_xor(v, 8, 64));
  v = fmaxf(v, __shfl_xor(v, 4, 64));
  v = fmaxf(v, __shfl_xor(v, 2, 64));
  v = fmaxf(v, __shfl_xor(v, 1, 64));
  return v;
}

// ---------------- kernels ----------------

// encoder: h = relu(LN(x @ W + b; g,be)) + cm*0.1   [N,64], one wave per row
__global__ __launch_bounds__(64) void encoder_kernel(
    const float* __restrict__ x, const float* __restrict__ W, const float* __restrict__ b,
    const float* __restrict__ g, const float* __restrict__ be, const float* __restrict__ cm,
    float* __restrict__ h) {
  __shared__ float xs[F_IN];
  int n = blockIdx.x, l = threadIdx.x;
  xs[l]      = x[(size_t)n * F_IN + l];
  xs[l + 64] = x[(size_t)n * F_IN + 64 + l];
  __syncthreads();
  float acc = b[l];
  #pragma unroll 8
  for (int k = 0; k < F_IN; k++) acc = fmaf(xs[k], W[k * HH + l], acc);
  float mu = waveSum(acc) * (1.0f / 64.0f);
  float d = acc - mu;
  float var = waveSum(d * d) * (1.0f / 64.0f);
  float y = fmaf(d / sqrtf(var + EPSF), g[l], be[l]);
  y = fmaxf(y, 0.0f);
  h[(size_t)n * HH + l] = fmaf(cm[l], 0.1f, y);
}

// C[NR,M] = A[NR,K] @ B[K,M] + bias ; 128x128 tile, BK=32, 256 thr, 8x8/thread
__global__ __launch_bounds__(256) void gemm128(
    const float* __restrict__ A, const float* __restrict__ B,
    const float* __restrict__ bias, float* __restrict__ C,
    int NR, int K, int M) {
  __shared__ float As[32][132];  // transposed: As[k][row]
  __shared__ float Bs[32][132];  // Bs[k][col]
  int t = threadIdx.x;
  int tx = t & 15, ty = t >> 4;
  int row0 = blockIdx.x * 128;
  int col0 = blockIdx.y * 128;
  float acc[8][8] = {};
  for (int k0 = 0; k0 < K; k0 += 32) {
    #pragma unroll
    for (int p = 0; p < 4; ++p) {       // A: 128 rows x 32 k  (1024 float4)
      int li = p * 256 + t;
      int r = li >> 3, kq = li & 7;
      int gr = row0 + r;
      float4 v = make_float4(0.f, 0.f, 0.f, 0.f);
      if (gr < NR) v = *(const float4*)(A + (size_t)gr * K + k0 + kq * 4);
      As[kq * 4 + 0][r] = v.x; As[kq * 4 + 1][r] = v.y;
      As[kq * 4 + 2][r] = v.z; As[kq * 4 + 3][r] = v.w;
    }
    #pragma unroll
    for (int p = 0; p < 4; ++p) {       // B: 32 k x 128 cols  (1024 float4)
      int li = p * 256 + t;
      int r = li >> 5, cq = li & 31;
      *(float4*)(&Bs[r][cq * 4]) = *(const float4*)(B + (size_t)(k0 + r) * M + col0 + cq * 4);
    }
    __syncthreads();
    #pragma unroll 8
    for (int kk = 0; kk < 32; ++kk) {
      float a[8], bb[8];
      *(float4*)&a[0]  = *(const float4*)&As[kk][ty * 8];
      *(float4*)&a[4]  = *(const float4*)&As[kk][ty * 8 + 4];
      *(float4*)&bb[0] = *(const float4*)&Bs[kk][tx * 8];
      *(float4*)&bb[4] = *(const float4*)&Bs[kk][tx * 8 + 4];
      #pragma unroll
      for (int i = 0; i < 8; i++)
        #pragma unroll
        for (int j = 0; j < 8; j++) acc[i][j] = fmaf(a[i], bb[j], acc[i][j]);
    }
    __syncthreads();
  }
  #pragma unroll
  for (int i = 0; i < 8; i++) {
    int r = row0 + ty * 8 + i;
    if (r >= NR) continue;
    #pragma unroll
    for (int j2 = 0; j2 < 2; j2++) {
      int c = col0 + tx * 8 + j2 * 4;
      float4 v;
      v.x = acc[i][j2 * 4 + 0] + bias[c + 0];
      v.y = acc[i][j2 * 4 + 1] + bias[c + 1];
      v.z = acc[i][j2 * 4 + 2] + bias[c + 2];
      v.w = acc[i][j2 * 4 + 3] + bias[c + 3];
      *(float4*)(C + (size_t)r * M + c) = v;
    }
  }
}

// In-place over Y[N,512]: o = relu(LN(Y; g,be)); feats (=|+=) o; Y = o + noise*cf
__global__ __launch_bounds__(256) void ln_relu_acc(
    float* __restrict__ Y, const float* __restrict__ g, const float* __restrict__ be,
    float* __restrict__ feats, int firstDepth, int writeCur,
    uint32_t k1, uint32_t k2, float cf) {
  int n = blockIdx.x, t = threadIdx.x;
  size_t base = (size_t)n * MM;
  float v0 = Y[base + t], v1 = Y[base + t + 256];
  int wid = t >> 6, lane = t & 63;
  __shared__ float red[8];
  float s = waveSum(v0 + v1);
  if (lane == 0) red[wid] = s;
  __syncthreads();
  float mu = (red[0] + red[1] + red[2] + red[3]) * (1.0f / 512.0f);
  float d0 = v0 - mu, d1 = v1 - mu;
  float q = waveSum(d0 * d0 + d1 * d1);
  if (lane == 0) red[4 + wid] = q;
  __syncthreads();
  float var = (red[4] + red[5] + red[6] + red[7]) * (1.0f / 512.0f);
  float inv = 1.0f / sqrtf(var + EPSF);
  float o0 = fmaxf(fmaf(d0 * inv, g[t], be[t]), 0.0f);
  float o1 = fmaxf(fmaf(d1 * inv, g[t + 256], be[t + 256]), 0.0f);
  if (firstDepth) { feats[base + t] = o0; feats[base + t + 256] = o1; }
  else            { feats[base + t] += o0; feats[base + t + 256] += o1; }
  if (writeCur) {
    Y[base + t]       = fmaf(jax_normal(k1, k2, (uint32_t)(base + t)), cf, o0);
    Y[base + t + 256] = fmaf(jax_normal(k1, k2, (uint32_t)(base + t + 256)), cf, o1);
  }
}

// a_i/a_j per node & head (feats/3 folded): one wave per node
__global__ __launch_bounds__(64) void gat_scores(
    const float* __restrict__ feats, const float* __restrict__ attL,
    float* __restrict__ ai, float* __restrict__ aj) {
  int n = blockIdx.x, l = threadIdx.x;
  const float inv3 = 1.0f / 3.0f;
  #pragma unroll
  for (int hh = 0; hh < HEADS; ++hh) {
    float v = feats[(size_t)n * MM + hh * HH + l] * inv3;
    float si = waveSum(v * attL[hh * 128 + l]);
    float sj = waveSum(v * attL[hh * 128 + 64 + l]);
    if (l == 0) { ai[n * HEADS + hh] = si; aj[n * HEADS + hh] = sj; }
  }
}

// -------- CSR build --------
__global__ __launch_bounds__(256) void csr_histo(const int* __restrict__ dst, int* __restrict__ deg) {
  int e = blockIdx.x * blockDim.x + threadIdx.x;
  if (e < EE) atomicAdd(&deg[dst[e]], 1);
}

__global__ __launch_bounds__(256) void csr_scan(const int* __restrict__ deg, int* __restrict__ offs) {
  __shared__ int part[256];
  int t = threadIdx.x;
  const int chunk = (NN + 255) / 256;  // 40
  int start = t * chunk;
  int s = 0;
  for (int j = 0; j < chunk; j++) { int i = start + j; if (i < NN) s += deg[i]; }
  part[t] = s; __syncthreads();
  for (int d = 1; d < 256; d <<= 1) {
    int v = (t >= d) ? part[t - d] : 0;
    __syncthreads();
    part[t] += v;
    __syncthreads();
  }
  int run = (t == 0) ? 0 : part[t - 1];
  for (int j = 0; j < chunk; j++) {
    int i = start + j;
    if (i < NN) { offs[i] = run; run += deg[i]; }
  }
  if (t == 0) offs[NN] = EE;
}

__global__ __launch_bounds__(256) void csr_fill(const int* __restrict__ src, const int* __restrict__ dst,
                                                int* __restrict__ pos, int* __restrict__ csrc) {
  int e = blockIdx.x * blockDim.x + threadIdx.x;
  if (e >= EE) return;
  int d = dst[e];
  int slot = atomicAdd(&pos[d], 1);
  csrc[slot] = src[e];
}

// -------- fused GAT: per-node softmax + gather-agg + head-mean + gate MLP + blend + LN --------
__global__ __launch_bounds__(64) void gat_fused(
    const int* __restrict__ offs, const int* __restrict__ csrc,
    const float* __restrict__ ai, const float* __restrict__ aj,
    const float* __restrict__ feats,
    const float* __restrict__ W1, const float* __restrict__ b1,
    const float* __restrict__ W2, const float* __restrict__ b2,
    float* __restrict__ h, float* __restrict__ resid) {
  int n = blockIdx.x, l = threadIdx.x;
  int e0 = offs[n], e1 = offs[n + 1];

  float aih[8];
  #pragma unroll
  for (int hh = 0; hh < HEADS; ++hh) aih[hh] = ai[n * HEADS + hh];

  float m[8], s[8];
  #pragma unroll
  for (int hh = 0; hh < HEADS; ++hh) { m[hh] = -1e30f; s[hh] = 0.0f; }

  // pass 1: online softmax stats (recompute alpha)
  for (int c = e0; c < e1; c += 64) {
    int idx = c + l;
    bool act = idx < e1;
    int sv = act ? csrc[idx] : 0;
    float a[8];
    #pragma unroll
    for (int hh = 0; hh < HEADS; ++hh) {
      float av = act ? (aih[hh] + aj[sv * HEADS + hh]) : -1e30f;
      a[hh] = (av >= 0.0f) ? av : 0.2f * av;
    }
    #pragma unroll
    for (int hh = 0; hh < HEADS; ++hh) {
      float cm = waveMax(a[hh]);
      float mnew = fmaxf(m[hh], cm);
      float ex = act ? expf(a[hh] - mnew) : 0.0f;
      float sc = (m[hh] > -1e29f) ? expf(m[hh] - mnew) : 0.0f;
      s[hh] = s[hh] * sc + waveSum(ex);
      m[hh] = mnew;
    }
  }
  const float inv3 = 1.0f / 3.0f;
  float invs[8];
  #pragma unroll
  for (int hh = 0; hh < HEADS; ++hh) invs[hh] = (s[hh] > 0.0f) ? (inv3 / s[hh]) : 0.0f;

  // pass 2: weights + gather-aggregate
  __shared__ int   sSrc[64];
  __shared__ float sEx[64][8];
  float acc[8];
  #pragma unroll
  for (int hh = 0; hh < HEADS; ++hh) acc[hh] = 0.0f;

  for (int c = e0; c < e1; c += 64) {
    int idx = c + l;
    bool act = idx < e1;
    if (act) {
      int sv = csrc[idx];
      sSrc[l] = sv;
      #pragma unroll
      for (int hh = 0; hh < HEADS; ++hh) {
        float av = aih[hh] + aj[sv * HEADS + hh];
        av = (av >= 0.0f) ? av : 0.2f * av;
        sEx[l][hh] = expf(av - m[hh]) * invs[hh];
      }
    }
    __syncthreads();
    int cnt = min(64, e1 - c);
    for (int j = 0; j < cnt; ++j) {
      const float* fr = feats + (size_t)sSrc[j] * MM;
      #pragma unroll
      for (int hh = 0; hh < HEADS; ++hh)
        acc[hh] = fmaf(fr[hh * HH + l], sEx[j][hh], acc[hh]);
    }
    __syncthreads();
  }

  // head mean
  float hn_l = 0.0f;
  #pragma unroll
  for (int hh = 0; hh < HEADS; ++hh) hn_l += acc[hh];
  hn_l *= 0.125f;

  // gate MLP (64 -> 128 relu -> 64), each thread does 2 hidden units
  __shared__ float hn[64];
  __shared__ float z[128];
  hn[l] = hn_l;
  __syncthreads();
  float z0 = b1[l], z1 = b1[l + 64];
  #pragma unroll 8
  for (int k = 0; k < 64; k++) {
    float hv = hn[k];
    z0 = fmaf(hv, W1[k * 128 + l], z0);
    z1 = fmaf(hv, W1[k * 128 + 64 + l], z1);
  }
  z[l] = fmaxf(z0, 0.0f);
  z[l + 64] = fmaxf(z1, 0.0f);
  __syncthreads();
  float y = b2[l];
  #pragma unroll 8
  for (int k = 0; k < 128; k++) y = fmaf(z[k], W2[k * 64 + l], y);
  float gate = 1.0f / (1.0f + expf(-tanhf(y)));
  float hp = h[(size_t)n * HH + l];
  float hb = gate * hn_l + (1.0f - gate) * hp;
  resid[(size_t)n * HH + l] += hb;
  float mu = waveSum(hb) * (1.0f / 64.0f);
  float dd = hb - mu;
  float var = waveSum(dd * dd) * (1.0f / 64.0f);
  h[(size_t)n * HH + l] = dd / sqrtf(var + EPSF);
}

// decoders; out layout: state[N], imp[N], chaos[N], evo[N*64], h_multi[N*64]
__global__ __launch_bounds__(64) void decoder_kernel(
    const float* __restrict__ resid,
    const float* __restrict__ dsW, const float* __restrict__ dsb,
    const float* __restrict__ diW, const float* __restrict__ dib,
    const float* __restrict__ dcW, const float* __restrict__ dcb,
    const float* __restrict__ deW, const float* __restrict__ deb,
    float* __restrict__ out) {
  __shared__ float hm[64];
  int n = blockIdx.x, l = threadIdx.x;
  float v = resid[(size_t)n * HH + l] * (1.0f / 6.0f);
  hm[l] = v;
  float s1 = waveSum(v * dsW[l]);
  float s2 = waveSum(v * diW[l]);
  float s3 = waveSum(v * dcW[l]);
  if (l == 0) {
    out[n]          = s1 + dsb[0];
    out[NN + n]     = s2 + dib[0];
    out[2 * NN + n] = s3 + dcb[0];
  }
  __syncthreads();
  float e = deb[l];
  #pragma unroll 8
  for (int k = 0; k < 64; k++) e = fmaf(hm[k], deW[k * OUT_DIM + l], e);
  out[3 * NN + (size_t)n * OUT_DIM + l] = e;
  out[3 * NN + (size_t)NN * OUT_DIM + (size_t)n * HH + l] = v;
}

// ---------------- launch ----------------
extern "C" void kernel_launch(void* const* d_in, const int* in_sizes, int n_in,
                              void* d_out, int out_size, void* d_ws, size_t ws_size,
                              hipStream_t stream) {
  const float* x        = (const float*)d_in[0];
  const int*   ei       = (const int*)d_in[1];
  const float* enc_W    = (const float*)d_in[2];
  const float* enc_b    = (const float*)d_in[3];
  const float* enc_g    = (const float*)d_in[4];
  const float* enc_beta = (const float*)d_in[5];
  const float* cm       = (const float*)d_in[6];
  const float* tW0 = (const float*)d_in[7];  const float* tb0 = (const float*)d_in[8];
  const float* tg0 = (const float*)d_in[9];  const float* tbe0 = (const float*)d_in[10];
  const float* tW1 = (const float*)d_in[11]; const float* tb1 = (const float*)d_in[12];
  const float* tg1 = (const float*)d_in[13]; const float* tbe1 = (const float*)d_in[14];
  const float* tW2 = (const float*)d_in[15]; const float* tb2 = (const float*)d_in[16];
  const float* tg2 = (const float*)d_in[17]; const float* tbe2 = (const float*)d_in[18];
  const float* att = (const float*)d_in[19];
  const float* evo_W1 = (const float*)d_in[20]; const float* evo_b1 = (const float*)d_in[21];
  const float* evo_W2 = (const float*)d_in[22]; const float* evo_b2 = (const float*)d_in[23];
  const float* dsW = (const float*)d_in[24]; const float* dsb = (const float*)d_in[25];
  const float* diW = (const float*)d_in[26]; const float* dib = (const float*)d_in[27];
  const float* dcW = (const float*)d_in[28]; const float* dcb = (const float*)d_in[29];
  const float* deW = (const float*)d_in[30]; const float* deb = (const float*)d_in[31];
  float* out = (float*)d_out;

  const int* src = ei;
  const int* dst = ei + EE;

  float* ws = (float*)d_ws;
  size_t o = 0;
  float* bufA  = ws + o; o += (size_t)NN * MM;
  float* bufB  = ws + o; o += (size_t)NN * MM;
  float* feats = ws + o; o += (size_t)NN * MM;
  float* h     = ws + o; o += (size_t)NN * HH;
  float* resid = ws + o; o += (size_t)NN * HH;
  float* ai    = ws + o; o += (size_t)NN * HEADS;
  float* aj    = ws + o; o += (size_t)NN * HEADS;
  int* deg  = (int*)(ws + o); o += NN;
  int* offs = (int*)(ws + o); o += NN + 1;
  int* pos  = (int*)(ws + o); o += NN;
  int* csrc = (int*)(ws + o); o += EE;
  (void)ws_size; (void)n_in; (void)in_sizes; (void)out_size;

  // CSR build (per call; edge_index constant within call)
  hipMemsetAsync(deg, 0, (size_t)NN * sizeof(int), stream);
  csr_histo<<<(EE + 255) / 256, 256, 0, stream>>>(dst, deg);
  csr_scan<<<1, 256, 0, stream>>>(deg, offs);
  hipMemcpyAsync(pos, offs, (size_t)NN * sizeof(int), hipMemcpyDeviceToDevice, stream);
  csr_fill<<<(EE + 255) / 256, 256, 0, stream>>>(src, dst, pos, csrc);

  encoder_kernel<<<NN, 64, 0, stream>>>(x, enc_W, enc_b, enc_g, enc_beta, cm, h);
  hipMemsetAsync(resid, 0, (size_t)NN * HH * sizeof(float), stream);

  dim3 gg((NN + 127) / 128, MM / 128);
  for (int i = 0; i < LL; ++i) {
    float cf = (float)(0.1 * (1.0 + 0.1 * (double)i));
    U2 fk0 = foldKey((uint32_t)(i * 10 + 0));
    U2 fk1 = foldKey((uint32_t)(i * 10 + 1));

    gemm128<<<gg, 256, 0, stream>>>(h,    tW0 + (size_t)i * HH * MM, tb0 + (size_t)i * MM, bufA, NN, HH, MM);
    ln_relu_acc<<<NN, 256, 0, stream>>>(bufA, tg0 + (size_t)i * MM, tbe0 + (size_t)i * MM, feats, 1, 1, fk0.a, fk0.b, cf);
    gemm128<<<gg, 256, 0, stream>>>(bufA, tW1 + (size_t)i * MM * MM, tb1 + (size_t)i * MM, bufB, NN, MM, MM);
    ln_relu_acc<<<NN, 256, 0, stream>>>(bufB, tg1 + (size_t)i * MM, tbe1 + (size_t)i * MM, feats, 0, 1, fk1.a, fk1.b, cf);
    gemm128<<<gg, 256, 0, stream>>>(bufB, tW2 + (size_t)i * MM * MM, tb2 + (size_t)i * MM, bufA, NN, MM, MM);
    ln_relu_acc<<<NN, 256, 0, stream>>>(bufA, tg2 + (size_t)i * MM, tbe2 + (size_t)i * MM, feats, 0, 0, 0u, 0u, 0.0f);

    gat_scores<<<NN, 64, 0, stream>>>(feats, att + (size_t)i * HEADS * 2 * HH, ai, aj);
    gat_fused<<<NN, 64, 0, stream>>>(offs, csrc, ai, aj, feats,
                                     evo_W1, evo_b1, evo_W2, evo_b2, h, resid);
  }

  decoder_kernel<<<NN, 64, 0, stream>>>(resid, dsW, dsb, diW, dib, dcW, dcb, deW, deb, out);
}

// Round 3
// 1515.704 us; speedup vs baseline: 2.8363x; 1.5339x over previous
//
#include <hip/hip_runtime.h>
#include <cstdint>
#include <cstddef>

// ---------------- constants ----------------
#define NN 10000
#define EE 160000
#define F_IN 128
#define HH 64
#define HEADS 8
#define LL 6
#define MM 512
#define OUT_DIM 64
#define EPSF 1e-5f

typedef unsigned short ushort;
typedef __attribute__((ext_vector_type(8))) short bf16x8;
typedef __attribute__((ext_vector_type(8))) unsigned short ushort8;
typedef __attribute__((ext_vector_type(4))) float f32x4;

// ---------------- threefry (JAX-compatible) ----------------
struct U2 { uint32_t a, b; };

__host__ __device__ constexpr uint32_t rotl32(uint32_t x, uint32_t d) {
  return (x << d) | (x >> (32u - d));
}

__host__ __device__ constexpr U2 threefry2x32(uint32_t k1, uint32_t k2, uint32_t x0, uint32_t x1) {
  uint32_t ks2 = k1 ^ k2 ^ 0x1BD11BDAu;
  x0 += k1; x1 += k2;
  x0 += x1; x1 = rotl32(x1, 13); x1 ^= x0;
  x0 += x1; x1 = rotl32(x1, 15); x1 ^= x0;
  x0 += x1; x1 = rotl32(x1, 26); x1 ^= x0;
  x0 += x1; x1 = rotl32(x1, 6);  x1 ^= x0;
  x0 += k2; x1 += ks2 + 1u;
  x0 += x1; x1 = rotl32(x1, 17); x1 ^= x0;
  x0 += x1; x1 = rotl32(x1, 29); x1 ^= x0;
  x0 += x1; x1 = rotl32(x1, 16); x1 ^= x0;
  x0 += x1; x1 = rotl32(x1, 24); x1 ^= x0;
  x0 += ks2; x1 += k1 + 2u;
  x0 += x1; x1 = rotl32(x1, 13); x1 ^= x0;
  x0 += x1; x1 = rotl32(x1, 15); x1 ^= x0;
  x0 += x1; x1 = rotl32(x1, 26); x1 ^= x0;
  x0 += x1; x1 = rotl32(x1, 6);  x1 ^= x0;
  x0 += k1; x1 += k2 + 3u;
  x0 += x1; x1 = rotl32(x1, 17); x1 ^= x0;
  x0 += x1; x1 = rotl32(x1, 29); x1 ^= x0;
  x0 += x1; x1 = rotl32(x1, 16); x1 ^= x0;
  x0 += x1; x1 = rotl32(x1, 24); x1 ^= x0;
  x0 += k2; x1 += ks2 + 4u;
  x0 += x1; x1 = rotl32(x1, 13); x1 ^= x0;
  x0 += x1; x1 = rotl32(x1, 15); x1 ^= x0;
  x0 += x1; x1 = rotl32(x1, 26); x1 ^= x0;
  x0 += x1; x1 = rotl32(x1, 6);  x1 ^= x0;
  x0 += ks2; x1 += k1 + 5u;
  return U2{x0, x1};
}

__host__ __device__ constexpr U2 foldKey(uint32_t data) {
  return threefry2x32(0u, 42u, 0u, data);
}

// XLA ErfInv f32 (Giles)
__device__ inline float erfinv_f32(float x) {
  float w = -log1pf(-x * x);
  float p;
  if (w < 5.0f) {
    w -= 2.5f;
    p = 2.81022636e-08f;
    p = fmaf(p, w, 3.43273939e-07f);
    p = fmaf(p, w, -3.5233877e-06f);
    p = fmaf(p, w, -4.39150654e-06f);
    p = fmaf(p, w, 0.00021858087f);
    p = fmaf(p, w, -0.00125372503f);
    p = fmaf(p, w, -0.00417768164f);
    p = fmaf(p, w, 0.246640727f);
    p = fmaf(p, w, 1.50140941f);
  } else {
    w = sqrtf(w) - 3.0f;
    p = -0.000200214257f;
    p = fmaf(p, w, 0.000100950558f);
    p = fmaf(p, w, 0.00134934322f);
    p = fmaf(p, w, -0.00367342844f);
    p = fmaf(p, w, 0.00573950773f);
    p = fmaf(p, w, -0.0076224613f);
    p = fmaf(p, w, 0.00943887047f);
    p = fmaf(p, w, 1.00167406f);
    p = fmaf(p, w, 2.83297682f);
  }
  return p * x;
}

__device__ inline float jax_normal(uint32_t k1, uint32_t k2, uint32_t idx) {
  U2 r = threefry2x32(k1, k2, 0u, idx);
  uint32_t bits = r.a ^ r.b;
  uint32_t fb = (bits >> 9) | 0x3f800000u;
  float f = __uint_as_float(fb) - 1.0f;
  const float lo = -0.99999994f;
  float u = f * 2.0f + lo;
  u = fmaxf(lo, u);
  return 1.41421356f * erfinv_f32(u);
}

// ---------------- helpers ----------------
__device__ inline float waveSum(float v) {
  v += __shfl_xor(v, 32, 64);
  v += __shfl_xor(v, 16, 64);
  v += __shfl_xor(v, 8, 64);
  v += __shfl_xor(v, 4, 64);
  v += __shfl_xor(v, 2, 64);
  v += __shfl_xor(v, 1, 64);
  return v;
}
__device__ inline float waveMax(float v) {
  v = fmaxf(v, __shfl_xor(v, 32, 64));
  v = fmaxf(v, __shfl_xor(v, 16, 64));
  v = fmaxf(v, __shfl_xor(v, 8, 64));
  v = fmaxf(v, __shfl_xor(v, 4, 64));
  v = fmaxf(v, __shfl_xor(v, 2, 64));
  v = fmaxf(v, __shfl_xor(v, 1, 64));
  return v;
}

__device__ inline ushort bf16rn(float x) {
  uint32_t u = __float_as_uint(x);
  uint32_t r = (u + 0x7fffu + ((u >> 16) & 1u)) >> 16;
  return (ushort)r;
}
__device__ inline float bf16tof(ushort h) {
  return __uint_as_float(((uint32_t)h) << 16);
}

// ---------------- kernels ----------------

// encoder: h = relu(LN(x @ W + b; g,be)) + cm*0.1   [N,64] + bf16 hi/lo planes
__global__ __launch_bounds__(64) void encoder_kernel(
    const float* __restrict__ x, const float* __restrict__ W, const float* __restrict__ b,
    const float* __restrict__ g, const float* __restrict__ be, const float* __restrict__ cm,
    float* __restrict__ h, ushort* __restrict__ hHi, ushort* __restrict__ hLo) {
  __shared__ float xs[F_IN];
  int n = blockIdx.x, l = threadIdx.x;
  xs[l]      = x[(size_t)n * F_IN + l];
  xs[l + 64] = x[(size_t)n * F_IN + 64 + l];
  __syncthreads();
  float acc = b[l];
  #pragma unroll 8
  for (int k = 0; k < F_IN; k++) acc = fmaf(xs[k], W[k * HH + l], acc);
  float mu = waveSum(acc) * (1.0f / 64.0f);
  float d = acc - mu;
  float var = waveSum(d * d) * (1.0f / 64.0f);
  float y = fmaf(d / sqrtf(var + EPSF), g[l], be[l]);
  y = fmaxf(y, 0.0f);
  float hv = fmaf(cm[l], 0.1f, y);
  h[(size_t)n * HH + l] = hv;
  ushort hi = bf16rn(hv);
  size_t oi = ((size_t)(l >> 5) * NN + n) * 32 + (l & 31);
  hHi[oi] = hi;
  hLo[oi] = bf16rn(hv - bf16tof(hi));
}

// weight convert+transpose: W[K][512] f32 -> [K/32][512][32] bf16 hi/lo, per layer (z)
__global__ __launch_bounds__(256) void wconv(
    const float* __restrict__ W, ushort* __restrict__ oh, ushort* __restrict__ ol, int K) {
  __shared__ ushort Th[64][40], Tl[64][40];
  int kt = blockIdx.x;
  int m0 = blockIdx.y * 64;
  int lay = blockIdx.z;
  const float* Wl = W + (size_t)lay * K * MM;
  ushort* ohl = oh + (size_t)lay * K * MM;
  ushort* oll = ol + (size_t)lay * K * MM;
  int t = threadIdx.x;
  #pragma unroll
  for (int p = 0; p < 2; ++p) {
    int li = p * 256 + t;
    int k = li >> 4, mg = (li & 15) * 4;
    float4 v = *(const float4*)(Wl + (size_t)(kt * 32 + k) * MM + m0 + mg);
    float vv[4] = {v.x, v.y, v.z, v.w};
    #pragma unroll
    for (int q = 0; q < 4; ++q) {
      ushort hi = bf16rn(vv[q]);
      Th[mg + q][k] = hi;
      Tl[mg + q][k] = bf16rn(vv[q] - bf16tof(hi));
    }
  }
  __syncthreads();
  #pragma unroll
  for (int p = 0; p < 2; ++p) {
    int li = p * 256 + t;              // 0..511 : plane|m|kh
    int plane = li >> 8;
    int rem = li & 255;
    int m = rem >> 2, kh = (rem & 3) * 8;
    size_t go = ((size_t)kt * MM + m0 + m) * 32 + kh;
    if (plane == 0) *(ushort8*)(ohl + go) = *(const ushort8*)&Th[m][kh];
    else            *(ushort8*)(oll + go) = *(const ushort8*)&Tl[m][kh];
  }
}

// MFMA GEMM: C[NR,512] = A[NR,K] @ W[K,512] + bias, split-bf16 (3 MFMA)
// A planes: [K/32][NR][32] bf16; W planes: [K/32][512][32] bf16 (k-tiled, transposed)
__global__ __launch_bounds__(256) void gemm_mfma(
    const ushort* __restrict__ Ahg, const ushort* __restrict__ Alg,
    const ushort* __restrict__ Whg, const ushort* __restrict__ Wlg,
    const float* __restrict__ bias, float* __restrict__ C,
    int NR, int K) {
  __shared__ ushort Ah[128][40], Al[128][40], Bh[64][40], Bl[64][40];
  int t = threadIdx.x, wid = t >> 6, lane = t & 63;
  int row0 = blockIdx.x * 128, col0 = blockIdx.y * 64;
  int wr = (wid & 1) * 64, wc = (wid >> 1) * 32;
  int lr = lane & 15, kh = (lane >> 4) * 8;
  f32x4 acc[4][2];
  #pragma unroll
  for (int i = 0; i < 4; i++)
    #pragma unroll
    for (int j = 0; j < 2; j++) acc[i][j] = (f32x4){0.f, 0.f, 0.f, 0.f};
  int nkt = K >> 5;
  for (int kt = 0; kt < nkt; ++kt) {
    const ushort* Abh = Ahg + (size_t)kt * NR * 32;
    const ushort* Abl = Alg + (size_t)kt * NR * 32;
    #pragma unroll
    for (int p = 0; p < 2; ++p) {        // A tile: 128 rows x 32 k, both planes
      int li = p * 256 + t;              // 0..511
      int r = li >> 2, kq = (li & 3) * 8;
      int gr = row0 + r;
      ushort8 vh = {0,0,0,0,0,0,0,0}, vl = {0,0,0,0,0,0,0,0};
      if (gr < NR) {
        vh = *(const ushort8*)(Abh + (size_t)gr * 32 + kq);
        vl = *(const ushort8*)(Abl + (size_t)gr * 32 + kq);
      }
      *(ushort8*)&Ah[r][kq] = vh;
      *(ushort8*)&Al[r][kq] = vl;
    }
    {
      int m = t >> 2, kq = (t & 3) * 8;  // B tile: 64 cols x 32 k
      size_t wo = (size_t)kt * MM * 32 + (size_t)(col0 + m) * 32 + kq;
      *(ushort8*)&Bh[m][kq] = *(const ushort8*)(Whg + wo);
      *(ushort8*)&Bl[m][kq] = *(const ushort8*)(Wlg + wo);
    }
    __syncthreads();
    bf16x8 bh[2], bl[2];
    #pragma unroll
    for (int cf = 0; cf < 2; ++cf) {
      bh[cf] = *(const bf16x8*)&Bh[wc + cf * 16 + lr][kh];
      bl[cf] = *(const bf16x8*)&Bl[wc + cf * 16 + lr][kh];
    }
    #pragma unroll
    for (int rf = 0; rf < 4; ++rf) {
      bf16x8 ah = *(const bf16x8*)&Ah[wr + rf * 16 + lr][kh];
      bf16x8 al = *(const bf16x8*)&Al[wr + rf * 16 + lr][kh];
      #pragma unroll
      for (int cf = 0; cf < 2; ++cf) {
        acc[rf][cf] = __builtin_amdgcn_mfma_f32_16x16x32_bf16(ah, bh[cf], acc[rf][cf], 0, 0, 0);
        acc[rf][cf] = __builtin_amdgcn_mfma_f32_16x16x32_bf16(ah, bl[cf], acc[rf][cf], 0, 0, 0);
        acc[rf][cf] = __builtin_amdgcn_mfma_f32_16x16x32_bf16(al, bh[cf], acc[rf][cf], 0, 0, 0);
      }
    }
    __syncthreads();
  }
  int r4 = (lane >> 4) * 4;
  #pragma unroll
  for (int cf = 0; cf < 2; ++cf) {
    int c = col0 + wc + cf * 16 + lr;
    float bc = bias[c];
    #pragma unroll
    for (int rf = 0; rf < 4; ++rf) {
      #pragma unroll
      for (int j = 0; j < 4; ++j) {
        int r = row0 + wr + rf * 16 + r4 + j;
        if (r < NR) C[(size_t)r * MM + c] = acc[rf][cf][j] + bc;
      }
    }
  }
}

// o = relu(LN(Y; g,be)); feats (=|+=) o; optional: bf16(o+noise) planes; optional: GAT scores
__global__ __launch_bounds__(256) void ln_relu_acc(
    const float* __restrict__ Y, const float* __restrict__ g, const float* __restrict__ be,
    float* __restrict__ feats, int firstDepth,
    ushort* __restrict__ outHi, ushort* __restrict__ outLo,
    uint32_t k1, uint32_t k2, float cf,
    const float* __restrict__ attL, float* __restrict__ ai, float* __restrict__ aj) {
  int n = blockIdx.x, t = threadIdx.x;
  size_t base = (size_t)n * MM;
  float v0 = Y[base + t], v1 = Y[base + t + 256];
  int wid = t >> 6, lane = t & 63;
  __shared__ float red[8];
  float s = waveSum(v0 + v1);
  if (lane == 0) red[wid] = s;
  __syncthreads();
  float mu = (red[0] + red[1] + red[2] + red[3]) * (1.0f / 512.0f);
  float d0 = v0 - mu, d1 = v1 - mu;
  float q = waveSum(d0 * d0 + d1 * d1);
  if (lane == 0) red[4 + wid] = q;
  __syncthreads();
  float var = (red[4] + red[5] + red[6] + red[7]) * (1.0f / 512.0f);
  float inv = 1.0f / sqrtf(var + EPSF);
  float o0 = fmaxf(fmaf(d0 * inv, g[t], be[t]), 0.0f);
  float o1 = fmaxf(fmaf(d1 * inv, g[t + 256], be[t + 256]), 0.0f);
  float f0, f1;
  if (firstDepth) { f0 = o0; f1 = o1; }
  else { f0 = feats[base + t] + o0; f1 = feats[base + t + 256] + o1; }
  feats[base + t] = f0; feats[base + t + 256] = f1;
  if (outHi) {
    float y0 = fmaf(jax_normal(k1, k2, (uint32_t)(base + t)), cf, o0);
    float y1 = fmaf(jax_normal(k1, k2, (uint32_t)(base + t + 256)), cf, o1);
    int c0 = t, c1 = t + 256;
    size_t i0 = ((size_t)(c0 >> 5) * NN + n) * 32 + (c0 & 31);
    size_t i1 = ((size_t)(c1 >> 5) * NN + n) * 32 + (c1 & 31);
    ushort h0 = bf16rn(y0), h1 = bf16rn(y1);
    outHi[i0] = h0; outLo[i0] = bf16rn(y0 - bf16tof(h0));
    outHi[i1] = h1; outLo[i1] = bf16rn(y1 - bf16tof(h1));
  }
  if (attL) {
    const float inv3 = 1.0f / 3.0f;
    float w0 = f0 * inv3, w1 = f1 * inv3;
    float si0 = waveSum(w0 * attL[wid * 128 + lane]);
    float sj0 = waveSum(w0 * attL[wid * 128 + 64 + lane]);
    float si1 = waveSum(w1 * attL[(wid + 4) * 128 + lane]);
    float sj1 = waveSum(w1 * attL[(wid + 4) * 128 + 64 + lane]);
    if (lane == 0) {
      ai[n * HEADS + wid] = si0;     aj[n * HEADS + wid] = sj0;
      ai[n * HEADS + wid + 4] = si1; aj[n * HEADS + wid + 4] = sj1;
    }
  }
}

// -------- CSR build --------
__global__ __launch_bounds__(256) void csr_histo(const int* __restrict__ dst, int* __restrict__ deg) {
  int e = blockIdx.x * blockDim.x + threadIdx.x;
  if (e < EE) atomicAdd(&deg[dst[e]], 1);
}

__global__ __launch_bounds__(256) void csr_scan(const int* __restrict__ deg, int* __restrict__ offs) {
  __shared__ int part[256];
  int t = threadIdx.x;
  const int chunk = (NN + 255) / 256;
  int start = t * chunk;
  int s = 0;
  for (int j = 0; j < chunk; j++) { int i = start + j; if (i < NN) s += deg[i]; }
  part[t] = s; __syncthreads();
  for (int d = 1; d < 256; d <<= 1) {
    int v = (t >= d) ? part[t - d] : 0;
    __syncthreads();
    part[t] += v;
    __syncthreads();
  }
  int run = (t == 0) ? 0 : part[t - 1];
  for (int j = 0; j < chunk; j++) {
    int i = start + j;
    if (i < NN) { offs[i] = run; run += deg[i]; }
  }
  if (t == 0) offs[NN] = EE;
}

__global__ __launch_bounds__(256) void csr_fill(const int* __restrict__ src, const int* __restrict__ dst,
                                                int* __restrict__ pos, int* __restrict__ csrc) {
  int e = blockIdx.x * blockDim.x + threadIdx.x;
  if (e >= EE) return;
  int d = dst[e];
  int slot = atomicAdd(&pos[d], 1);
  csrc[slot] = src[e];
}

// -------- fused GAT (256 thr: wave w owns heads 2w,2w+1) --------
__global__ __launch_bounds__(256) void gat_fused(
    const int* __restrict__ offs, const int* __restrict__ csrc,
    const float* __restrict__ ai, const float* __restrict__ aj,
    const float* __restrict__ feats,
    const float* __restrict__ W1, const float* __restrict__ b1,
    const float* __restrict__ W2, const float* __restrict__ b2,
    float* __restrict__ h, float* __restrict__ resid,
    ushort* __restrict__ hHi, ushort* __restrict__ hLo) {
  int n = blockIdx.x, t = threadIdx.x, wid = t >> 6, l = t & 63;
  int e0 = offs[n], e1 = offs[n + 1];
  int hA = wid * 2;
  float2 aiv = *(const float2*)&ai[n * HEADS + hA];

  float m0 = -1e30f, m1 = -1e30f, s0 = 0.f, s1 = 0.f;
  for (int c = e0; c < e1; c += 64) {
    int idx = c + l;
    bool act = idx < e1;
    float a0 = -1e30f, a1 = -1e30f;
    if (act) {
      int sv = csrc[idx];
      float2 ajv = *(const float2*)&aj[sv * HEADS + hA];
      a0 = aiv.x + ajv.x; a0 = (a0 >= 0.f) ? a0 : 0.2f * a0;
      a1 = aiv.y + ajv.y; a1 = (a1 >= 0.f) ? a1 : 0.2f * a1;
    }
    float cm0 = waveMax(a0), cm1 = waveMax(a1);
    float mn0 = fmaxf(m0, cm0), mn1 = fmaxf(m1, cm1);
    float e0v = act ? expf(a0 - mn0) : 0.f;
    float e1v = act ? expf(a1 - mn1) : 0.f;
    float sc0 = (m0 > -1e29f) ? expf(m0 - mn0) : 0.f;
    float sc1 = (m1 > -1e29f) ? expf(m1 - mn1) : 0.f;
    s0 = s0 * sc0 + waveSum(e0v);
    s1 = s1 * sc1 + waveSum(e1v);
    m0 = mn0; m1 = mn1;
  }
  const float inv3 = 1.0f / 3.0f;
  float is0 = (s0 > 0.f) ? inv3 / s0 : 0.f;
  float is1 = (s1 > 0.f) ? inv3 / s1 : 0.f;

  __shared__ int sSrc[64];
  __shared__ float sEx[8][64];
  float acc0 = 0.f, acc1 = 0.f;
  for (int c = e0; c < e1; c += 64) {
    int idx = c + l;
    bool act = idx < e1;
    if (act) {
      int sv = csrc[idx];
      if (wid == 0) sSrc[l] = sv;
      float2 ajv = *(const float2*)&aj[sv * HEADS + hA];
      float a0 = aiv.x + ajv.x; a0 = (a0 >= 0.f) ? a0 : 0.2f * a0;
      float a1 = aiv.y + ajv.y; a1 = (a1 >= 0.f) ? a1 : 0.2f * a1;
      sEx[hA][l]     = expf(a0 - m0) * is0;
      sEx[hA + 1][l] = expf(a1 - m1) * is1;
    }
    __syncthreads();
    int cnt = min(64, e1 - c);
    for (int j = 0; j < cnt; ++j) {
      const float* fr = feats + (size_t)sSrc[j] * MM;
      acc0 = fmaf(fr[hA * HH + l],       sEx[hA][j],     acc0);
      acc1 = fmaf(fr[(hA + 1) * HH + l], sEx[hA + 1][j], acc1);
    }
    __syncthreads();
  }

  __shared__ float hacc[4][64];
  hacc[wid][l] = acc0 + acc1;
  __syncthreads();
  __shared__ float hn[64];
  __shared__ float z[128];
  if (t < 64) hn[t] = (hacc[0][t] + hacc[1][t] + hacc[2][t] + hacc[3][t]) * 0.125f;
  __syncthreads();
  if (t < 128) {
    float zz = b1[t];
    #pragma unroll 8
    for (int k = 0; k < 64; k++) zz = fmaf(hn[k], W1[k * 128 + t], zz);
    z[t] = fmaxf(zz, 0.f);
  }
  __syncthreads();
  if (t < 64) {
    float y = b2[t];
    #pragma unroll 8
    for (int k = 0; k < 128; k++) y = fmaf(z[k], W2[k * 64 + t], y);
    float gate = 1.0f / (1.0f + expf(-tanhf(y)));
    float hp = h[(size_t)n * HH + t];
    float hb = gate * hn[t] + (1.0f - gate) * hp;
    resid[(size_t)n * HH + t] += hb;
    float mu = waveSum(hb) * (1.0f / 64.0f);
    float dd = hb - mu;
    float var = waveSum(dd * dd) * (1.0f / 64.0f);
    float hv = dd / sqrtf(var + EPSF);
    h[(size_t)n * HH + t] = hv;
    ushort hi = bf16rn(hv);
    size_t oi = ((size_t)(t >> 5) * NN + n) * 32 + (t & 31);
    hHi[oi] = hi;
    hLo[oi] = bf16rn(hv - bf16tof(hi));
  }
}

// decoders; out layout: state[N], imp[N], chaos[N], evo[N*64], h_multi[N*64]
__global__ __launch_bounds__(64) void decoder_kernel(
    const float* __restrict__ resid,
    const float* __restrict__ dsW, const float* __restrict__ dsb,
    const float* __restrict__ diW, const float* __restrict__ dib,
    const float* __restrict__ dcW, const float* __restrict__ dcb,
    const float* __restrict__ deW, const float* __restrict__ deb,
    float* __restrict__ out) {
  __shared__ float hm[64];
  int n = blockIdx.x, l = threadIdx.x;
  float v = resid[(size_t)n * HH + l] * (1.0f / 6.0f);
  hm[l] = v;
  float s1 = waveSum(v * dsW[l]);
  float s2 = waveSum(v * diW[l]);
  float s3 = waveSum(v * dcW[l]);
  if (l == 0) {
    out[n]          = s1 + dsb[0];
    out[NN + n]     = s2 + dib[0];
    out[2 * NN + n] = s3 + dcb[0];
  }
  __syncthreads();
  float e = deb[l];
  #pragma unroll 8
  for (int k = 0; k < 64; k++) e = fmaf(hm[k], deW[k * OUT_DIM + l], e);
  out[3 * NN + (size_t)n * OUT_DIM + l] = e;
  out[3 * NN + (size_t)NN * OUT_DIM + (size_t)n * HH + l] = v;
}

// ---------------- launch ----------------
extern "C" void kernel_launch(void* const* d_in, const int* in_sizes, int n_in,
                              void* d_out, int out_size, void* d_ws, size_t ws_size,
                              hipStream_t stream) {
  const float* x        = (const float*)d_in[0];
  const int*   ei       = (const int*)d_in[1];
  const float* enc_W    = (const float*)d_in[2];
  const float* enc_b    = (const float*)d_in[3];
  const float* enc_g    = (const float*)d_in[4];
  const float* enc_beta = (const float*)d_in[5];
  const float* cm       = (const float*)d_in[6];
  const float* tW0 = (const float*)d_in[7];  const float* tb0 = (const float*)d_in[8];
  const float* tg0 = (const float*)d_in[9];  const float* tbe0 = (const float*)d_in[10];
  const float* tW1 = (const float*)d_in[11]; const float* tb1 = (const float*)d_in[12];
  const float* tg1 = (const float*)d_in[13]; const float* tbe1 = (const float*)d_in[14];
  const float* tW2 = (const float*)d_in[15]; const float* tb2 = (const float*)d_in[16];
  const float* tg2 = (const float*)d_in[17]; const float* tbe2 = (const float*)d_in[18];
  const float* att = (const float*)d_in[19];
  const float* evo_W1 = (const float*)d_in[20]; const float* evo_b1 = (const float*)d_in[21];
  const float* evo_W2 = (const float*)d_in[22]; const float* evo_b2 = (const float*)d_in[23];
  const float* dsW = (const float*)d_in[24]; const float* dsb = (const float*)d_in[25];
  const float* diW = (const float*)d_in[26]; const float* dib = (const float*)d_in[27];
  const float* dcW = (const float*)d_in[28]; const float* dcb = (const float*)d_in[29];
  const float* deW = (const float*)d_in[30]; const float* deb = (const float*)d_in[31];
  float* out = (float*)d_out;

  const int* src = ei;
  const int* dst = ei + EE;

  float* ws = (float*)d_ws;
  size_t o = 0;
  float* bufA  = ws + o; o += (size_t)NN * MM;
  float* feats = ws + o; o += (size_t)NN * MM;
  float* h     = ws + o; o += (size_t)NN * HH;
  float* resid = ws + o; o += (size_t)NN * HH;
  float* ai    = ws + o; o += (size_t)NN * HEADS;
  float* aj    = ws + o; o += (size_t)NN * HEADS;
  int* deg  = (int*)(ws + o); o += NN;
  int* offs = (int*)(ws + o); o += NN + 2;
  int* pos  = (int*)(ws + o); o += NN;
  int* csrc = (int*)(ws + o); o += EE;
  o = (o + 7) & ~(size_t)7;  // 16B align for ushort8 region
  ushort* us = (ushort*)(ws + o);
  size_t uo = 0;
  ushort* W0h = us + uo; uo += (size_t)LL * HH * MM;
  ushort* W0l = us + uo; uo += (size_t)LL * HH * MM;
  ushort* W1h = us + uo; uo += (size_t)LL * MM * MM;
  ushort* W1l = us + uo; uo += (size_t)LL * MM * MM;
  ushort* W2h = us + uo; uo += (size_t)LL * MM * MM;
  ushort* W2l = us + uo; uo += (size_t)LL * MM * MM;
  ushort* actHi = us + uo; uo += (size_t)NN * MM;
  ushort* actLo = us + uo; uo += (size_t)NN * MM;
  ushort* hHi = us + uo; uo += (size_t)NN * HH;
  ushort* hLo = us + uo; uo += (size_t)NN * HH;
  (void)ws_size; (void)n_in; (void)in_sizes; (void)out_size;

  // one-time weight conversion (deterministic, runs every call)
  wconv<<<dim3(2, 8, 6), 256, 0, stream>>>(tW0, W0h, W0l, HH);
  wconv<<<dim3(16, 8, 6), 256, 0, stream>>>(tW1, W1h, W1l, MM);
  wconv<<<dim3(16, 8, 6), 256, 0, stream>>>(tW2, W2h, W2l, MM);

  // CSR build
  hipMemsetAsync(deg, 0, (size_t)NN * sizeof(int), stream);
  csr_histo<<<(EE + 255) / 256, 256, 0, stream>>>(dst, deg);
  csr_scan<<<1, 256, 0, stream>>>(deg, offs);
  hipMemcpyAsync(pos, offs, (size_t)NN * sizeof(int), hipMemcpyDeviceToDevice, stream);
  csr_fill<<<(EE + 255) / 256, 256, 0, stream>>>(src, dst, pos, csrc);

  encoder_kernel<<<NN, 64, 0, stream>>>(x, enc_W, enc_b, enc_g, enc_beta, cm, h, hHi, hLo);
  hipMemsetAsync(resid, 0, (size_t)NN * HH * sizeof(float), stream);

  dim3 gg((NN + 127) / 128, MM / 64);
  for (int i = 0; i < LL; ++i) {
    float cf = (float)(0.1 * (1.0 + 0.1 * (double)i));
    U2 fk0 = foldKey((uint32_t)(i * 10 + 0));
    U2 fk1 = foldKey((uint32_t)(i * 10 + 1));
    const float* attL = att + (size_t)i * HEADS * 2 * HH;

    gemm_mfma<<<gg, 256, 0, stream>>>(hHi, hLo,
        W0h + (size_t)i * HH * MM, W0l + (size_t)i * HH * MM, tb0 + (size_t)i * MM,
        bufA, NN, HH);
    ln_relu_acc<<<NN, 256, 0, stream>>>(bufA, tg0 + (size_t)i * MM, tbe0 + (size_t)i * MM,
        feats, 1, actHi, actLo, fk0.a, fk0.b, cf, nullptr, nullptr, nullptr);
    gemm_mfma<<<gg, 256, 0, stream>>>(actHi, actLo,
        W1h + (size_t)i * MM * MM, W1l + (size_t)i * MM * MM, tb1 + (size_t)i * MM,
        bufA, NN, MM);
    ln_relu_acc<<<NN, 256, 0, stream>>>(bufA, tg1 + (size_t)i * MM, tbe1 + (size_t)i * MM,
        feats, 0, actHi, actLo, fk1.a, fk1.b, cf, nullptr, nullptr, nullptr);
    gemm_mfma<<<gg, 256, 0, stream>>>(actHi, actLo,
        W2h + (size_t)i * MM * MM, W2l + (size_t)i * MM * MM, tb2 + (size_t)i * MM,
        bufA, NN, MM);
    ln_relu_acc<<<NN, 256, 0, stream>>>(bufA, tg2 + (size_t)i * MM, tbe2 + (size_t)i * MM,
        feats, 0, nullptr, nullptr, 0u, 0u, 0.f, attL, ai, aj);

    gat_fused<<<NN, 256, 0, stream>>>(offs, csrc, ai, aj, feats,
        evo_W1, evo_b1, evo_W2, evo_b2, h, resid, hHi, hLo);
  }

  decoder_kernel<<<NN, 64, 0, stream>>>(resid, dsW, dsb, diW, dib, dcW, dcb, deW, deb, out);
}